// Round 7
// baseline (103950.293 us; speedup 1.0000x reference)
//
#include <hip/hip_runtime.h>
#include <stdint.h>

#define TT 256
#define BB 64
#define EE 512
#define HH 1024

struct P {
  const float *WihA[2], *WhhA[2], *bihA[2], *bhhA[2];  // layer 0 (fwd, bwd)
  const float *WihB[2], *WhhB[2], *bihB[2], *bhhB[2];  // layer 1 (fwd, bwd)
  const int* lens;
  const float* x;           // [T][B][E] f32
  float* out;               // [2][T][B][2][H] f32  (d_out is FLOAT32)
  float *hA, *cA, *hB, *cB; // h: [2buf][2unit][B][H]; c: [2unit][B][H]
};

__global__ void prep_x(const int* ids, const float* emb, float* x) {
  const int rowid = blockIdx.x;  // t*B + b
  const int id = ids[rowid];
  const int e = threadIdx.x * 4;
  *(float4*)(x + (size_t)rowid * EE + e) = *(const float4*)(emb + (size_t)id * EE + e);
}

// Layer 0, one time step, both directions. grid 512 = unit(2) x jb(128) x ch(2).
__global__ __launch_bounds__(256) void stepA(P p, int s) {
  const int unit = blockIdx.x & 1;
  const int jb = (blockIdx.x >> 1) & 127;
  const int ch = blockIdx.x >> 8;
  const int row = threadIdx.x & 63;
  const int col = jb * 8 + ch * 4 + (threadIdx.x >> 6);
  const int dir = unit;
  const int t = dir ? (TT - 1 - s) : s;

  float acc[4];
#pragma unroll
  for (int g = 0; g < 4; ++g)
    acc[g] = p.bihA[unit][g * HH + col] + p.bhhA[unit][g * HH + col];

  // x part (K = 512), fp32
  const float* xr = p.x + ((size_t)t * BB + row) * EE;
  const float* Wih = p.WihA[unit];
  for (int kb = 0; kb < EE; kb += 4) {
    const float4 a = *(const float4*)(xr + kb);
#pragma unroll
    for (int g = 0; g < 4; ++g) {
      const float4 w = *(const float4*)(Wih + (size_t)(g * HH + col) * EE + kb);
      acc[g] = fmaf(a.w, w.w, fmaf(a.z, w.z, fmaf(a.y, w.y, fmaf(a.x, w.x, acc[g]))));
    }
  }
  // h part (K = 1024), fp32 from carried-h plane
  const float* hprev = p.hA + (((size_t)((s - 1) & 1) * 2 + unit) * BB + row) * HH;
  float hp = 0.f;
  if (s > 0) {
    hp = hprev[col];
    const float* Whh = p.WhhA[unit];
    for (int kb = 0; kb < HH; kb += 4) {
      const float4 a = *(const float4*)(hprev + kb);
#pragma unroll
      for (int g = 0; g < 4; ++g) {
        const float4 w = *(const float4*)(Whh + (size_t)(g * HH + col) * HH + kb);
        acc[g] = fmaf(a.w, w.w, fmaf(a.z, w.z, fmaf(a.y, w.y, fmaf(a.x, w.x, acc[g]))));
      }
    }
  }

  const bool m = (t < p.lens[row]);
  const float iv = 1.f / (1.f + expf(-acc[0]));
  const float fv = 1.f / (1.f + expf(-acc[1]));
  const float gv = tanhf(acc[2]);
  const float ov = 1.f / (1.f + expf(-acc[3]));
  const size_t ci = ((size_t)unit * BB + row) * HH + col;
  const float c0 = (s > 0) ? p.cA[ci] : 0.f;
  const float cn = fv * c0 + iv * gv;
  const float hn = ov * tanhf(cn);
  p.cA[ci] = m ? cn : c0;
  p.hA[(((size_t)(s & 1) * 2 + unit) * BB + row) * HH + col] = m ? hn : hp;

  // masked layer-0 output, f32, straight into d_out L0 slot
  p.out[((size_t)(dir * TT + t) * BB + row) * (2 * HH) + col] = m ? hn : 0.f;
}

// Layer 1, one time step. Writes FINAL f32 output (mask ? h1 + y0 : 0).
__global__ __launch_bounds__(256) void stepB(P p, int s) {
  const int unit = blockIdx.x & 1;
  const int jb = (blockIdx.x >> 1) & 127;
  const int ch = blockIdx.x >> 8;
  const int row = threadIdx.x & 63;
  const int col = jb * 8 + ch * 4 + (threadIdx.x >> 6);
  const int dir = unit;
  const int t = dir ? (TT - 1 - s) : s;

  float acc[4];
#pragma unroll
  for (int g = 0; g < 4; ++g)
    acc[g] = p.bihB[unit][g * HH + col] + p.bhhB[unit][g * HH + col];

  // y0 input part (K = 1024): f32 exact from d_out L0 slot
  const float* yr = p.out + ((size_t)(dir * TT + t) * BB + row) * (2 * HH);
  const float* Wih = p.WihB[unit];
  for (int kb = 0; kb < HH; kb += 4) {
    const float4 a = *(const float4*)(yr + kb);
#pragma unroll
    for (int g = 0; g < 4; ++g) {
      const float4 w = *(const float4*)(Wih + (size_t)(g * HH + col) * HH + kb);
      acc[g] = fmaf(a.w, w.w, fmaf(a.z, w.z, fmaf(a.y, w.y, fmaf(a.x, w.x, acc[g]))));
    }
  }
  // h1 recurrent part (K = 1024), fp32 exact
  const float* hprev = p.hB + (((size_t)((s - 1) & 1) * 2 + unit) * BB + row) * HH;
  float hp = 0.f;
  if (s > 0) {
    hp = hprev[col];
    const float* Whh = p.WhhB[unit];
    for (int kb = 0; kb < HH; kb += 4) {
      const float4 a = *(const float4*)(hprev + kb);
#pragma unroll
      for (int g = 0; g < 4; ++g) {
        const float4 w = *(const float4*)(Whh + (size_t)(g * HH + col) * HH + kb);
        acc[g] = fmaf(a.w, w.w, fmaf(a.z, w.z, fmaf(a.y, w.y, fmaf(a.x, w.x, acc[g]))));
      }
    }
  }

  const bool m = (t < p.lens[row]);
  const float iv = 1.f / (1.f + expf(-acc[0]));
  const float fv = 1.f / (1.f + expf(-acc[1]));
  const float gv = tanhf(acc[2]);
  const float ov = 1.f / (1.f + expf(-acc[3]));
  const size_t ci = ((size_t)unit * BB + row) * HH + col;
  const float c0 = (s > 0) ? p.cB[ci] : 0.f;
  const float cn = fv * c0 + iv * gv;
  const float hn = ov * tanhf(cn);
  p.cB[ci] = m ? cn : c0;
  p.hB[(((size_t)(s & 1) * 2 + unit) * BB + row) * HH + col] = m ? hn : hp;

  const float y0v = yr[col];  // this thread's own y0 (f32 exact)
  p.out[((size_t)(dir * TT + t) * BB + row) * (2 * HH) + HH + col] =
      m ? (hn + y0v) : 0.f;
}

extern "C" void kernel_launch(void* const* d_in, const int* in_sizes, int n_in,
                              void* d_out, int out_size, void* d_ws, size_t ws_size,
                              hipStream_t stream) {
  // Loud-fail structural checks: mismatch leaves d_out zeroed (absmax = max|ref|).
  if (n_in != 19) return;
  if (in_sizes[0] != TT * BB || in_sizes[1] != BB) return;
  if (in_sizes[2] != 32000 * EE) return;
  if (in_sizes[3] != 4 * HH * EE || in_sizes[4] != 4 * HH * HH) return;    // fw0
  if (in_sizes[5] != 4 * HH || in_sizes[6] != 4 * HH) return;
  if (in_sizes[7] != 4 * HH * HH || in_sizes[8] != 4 * HH * HH) return;    // fw1
  if (in_sizes[11] != 4 * HH * EE || in_sizes[12] != 4 * HH * HH) return;  // bw0
  if (in_sizes[15] != 4 * HH * HH || in_sizes[16] != 4 * HH * HH) return;  // bw1
  if (out_size != 2 * TT * BB * 2 * HH) return;
  if (ws_size < 36700160) return;

  char* ws = (char*)d_ws;
  float* xf = (float*)ws;                // 33,554,432 B : [T][B][E] f32
  float* hA = (float*)(ws + 33554432);   //  1,048,576 B : [2][2][B][H]
  float* cA = (float*)(ws + 34603008);   //    524,288 B : [2][B][H]
  float* hB = (float*)(ws + 35127296);   //  1,048,576 B
  float* cB = (float*)(ws + 36175872);   //    524,288 B

  P p;
  p.WihA[0] = (const float*)d_in[3];  p.WhhA[0] = (const float*)d_in[4];
  p.bihA[0] = (const float*)d_in[5];  p.bhhA[0] = (const float*)d_in[6];
  p.WihA[1] = (const float*)d_in[11]; p.WhhA[1] = (const float*)d_in[12];
  p.bihA[1] = (const float*)d_in[13]; p.bhhA[1] = (const float*)d_in[14];
  p.WihB[0] = (const float*)d_in[7];  p.WhhB[0] = (const float*)d_in[8];
  p.bihB[0] = (const float*)d_in[9];  p.bhhB[0] = (const float*)d_in[10];
  p.WihB[1] = (const float*)d_in[15]; p.WhhB[1] = (const float*)d_in[16];
  p.bihB[1] = (const float*)d_in[17]; p.bhhB[1] = (const float*)d_in[18];
  p.lens = (const int*)d_in[1];
  p.x = xf;
  p.out = (float*)d_out;
  p.hA = hA; p.cA = cA; p.hB = hB; p.cB = cB;

  prep_x<<<TT * BB, 128, 0, stream>>>((const int*)d_in[0], (const float*)d_in[2], xf);
  for (int s = 0; s < TT; ++s)
    stepA<<<512, 256, 0, stream>>>(p, s);
  for (int s = 0; s < TT; ++s)
    stepB<<<512, 256, 0, stream>>>(p, s);
}

// Round 8
// 23472.861 us; speedup vs baseline: 4.4285x; 4.4285x over previous
//
#include <hip/hip_runtime.h>
#include <stdint.h>

#define TT 256
#define BB 64
#define EE 512
#define HH 1024

typedef short s8v __attribute__((ext_vector_type(8)));
typedef float f4v __attribute__((ext_vector_type(4)));
typedef unsigned short u16;

static __device__ __forceinline__ u16 f2bf(float f) {
  uint32_t u = __float_as_uint(f);
  return (u16)((u + 0x7fffu + ((u >> 16) & 1u)) >> 16);  // RNE
}
static __device__ __forceinline__ float bf2f(u16 b) {
  return __uint_as_float(((uint32_t)b) << 16);
}

struct P {
  const int* ids; const int* lens; const float* emb;
  const float* bih[2][2]; const float* bhh[2][2];  // [layer][unit]
  const u16* W[2][2][2];   // [layer][unit][plane hi/mid], frag-ready layout
  float* out;              // [2][T][B][2][H] f32
  float* h[2];             // [2buf][2unit][B][H] f32 (carried h, exact)
  u16* hpl[2];             // [2buf][2unit][3][B][H] bf16 planes of carried h
  float* c[2];             // [2unit][B][H] f32
  u16* y0pl;               // [2unit][3][B][H] bf16 planes of masked y0 (depth-1)
};

// Split f32 weights into hi/mid bf16 planes, frag-ready layout:
// dst[jb][kt][kg][c][e] where k = kt*32+kg*8+e, gate-col n = (c>>3)*H + jb*8 + (c&7)
__global__ void prep_w(const float* Wih, const float* Whh, int KX, int K,
                       u16* dH, u16* dM) {
  const size_t total = (size_t)128 * K * 32;
  for (size_t idx = (size_t)blockIdx.x * 256 + threadIdx.x; idx < total;
       idx += (size_t)gridDim.x * 256) {
    const int c = (int)(idx & 31);
    const int k = (int)((idx >> 5) % K);
    const int jb = (int)(idx / ((size_t)K * 32));
    const int n = (c >> 3) * HH + jb * 8 + (c & 7);
    const float v = (k < KX) ? Wih[(size_t)n * KX + k] : Whh[(size_t)n * HH + (k - KX)];
    const u16 h = f2bf(v);
    const u16 m = f2bf(v - bf2f(h));
    const size_t off = ((size_t)jb * (K / 32) + (k >> 5)) * 1024 +
                       ((k >> 3) & 3) * 256 + c * 8 + (k & 7);
    dH[off] = h; dM[off] = m;
  }
}

// One time step of one layer, both directions.
// grid 256 = unit(2) x jb(128); block 256 = 4 waves; wave = 16 rows x 32 gate-cols.
template <int LAYER, int K, int KX, int KTQ>
__global__ __launch_bounds__(256) void step_k(P p, int s) {
  constexpr int NST = K / 32 / KTQ;
  __shared__ __align__(16) u16 lH[KTQ * 1024];
  __shared__ __align__(16) u16 lM[KTQ * 1024];
  __shared__ float epi[4 * 32 * 17];
  const int tid = threadIdx.x;
  const int w = tid >> 6, l = tid & 63, lr = l & 15, kgq = l >> 4;
  const int unit = blockIdx.x >> 7;
  const int jb = blockIdx.x & 127;
  const int dir = unit;
  const int t = dir ? (TT - 1 - s) : s;
  const int row = w * 16 + lr;   // A-frag row (batch), row = lane&15 convention

  const u16* WH = p.W[LAYER][unit][0] + (size_t)jb * (K / 32) * 1024;
  const u16* WM = p.W[LAYER][unit][1] + (size_t)jb * (K / 32) * 1024;

  const int pb = (s - 1) & 1;
  const u16* hp3 = p.hpl[LAYER] + (size_t)(pb * 2 + unit) * 3 * BB * HH;
  const u16* y3  = p.y0pl + (size_t)unit * 3 * BB * HH;
  const float* xsrc = nullptr;
  if (LAYER == 0) {
    const int id = p.ids[t * BB + row];
    xsrc = p.emb + (size_t)id * EE;
  }

  f4v acc[2];
  { f4v z = {0.f, 0.f, 0.f, 0.f}; acc[0] = z; acc[1] = z; }

  for (int q = 0; q < NST; ++q) {
    __syncthreads();
    {  // flat stage copy of this K-chunk (both planes), frag-ready already
      const uint4* sH = (const uint4*)(WH + (size_t)q * KTQ * 1024);
      const uint4* sM = (const uint4*)(WM + (size_t)q * KTQ * 1024);
      uint4* dH = (uint4*)lH; uint4* dM = (uint4*)lM;
      for (int i = tid; i < KTQ * 128; i += 256) { dH[i] = sH[i]; dM[i] = sM[i]; }
    }
    __syncthreads();
    for (int ktl = 0; ktl < KTQ; ++ktl) {
      const int ktg = q * KTQ + ktl;
      const int k0 = ktg * 32 + kgq * 8;
      s8v a0, a1, a2;
      bool three;
      if (LAYER == 0 && k0 < KX) {           // x part: gather + 2-plane split
        const float4 f0 = *(const float4*)(xsrc + k0);
        const float4 f1 = *(const float4*)(xsrc + k0 + 4);
        const float tf[8] = {f0.x, f0.y, f0.z, f0.w, f1.x, f1.y, f1.z, f1.w};
#pragma unroll
        for (int e = 0; e < 8; ++e) {
          const u16 hh = f2bf(tf[e]);
          a0[e] = (short)hh;
          a1[e] = (short)f2bf(tf[e] - bf2f(hh));
        }
        three = false;
      } else if (LAYER == 1 && k0 < KX) {    // y0 planes (3-plane, pre-split)
        const size_t o = (size_t)row * HH + k0;
        a0 = *(const s8v*)(y3 + o);
        a1 = *(const s8v*)(y3 + (size_t)BB * HH + o);
        a2 = *(const s8v*)(y3 + (size_t)2 * BB * HH + o);
        three = true;
      } else {                               // recurrent h planes
        if (s == 0) continue;
        const size_t o = (size_t)row * HH + (k0 - KX);
        a0 = *(const s8v*)(hp3 + o);
        a1 = *(const s8v*)(hp3 + (size_t)BB * HH + o);
        a2 = *(const s8v*)(hp3 + (size_t)2 * BB * HH + o);
        three = true;
      }
#pragma unroll
      for (int ct = 0; ct < 2; ++ct) {
        const int bo = ((ktl * 4 + kgq) * 32 + ct * 16 + lr) * 8;
        const s8v bh = *(const s8v*)(lH + bo);
        const s8v bm = *(const s8v*)(lM + bo);
        acc[ct] = __builtin_amdgcn_mfma_f32_16x16x32_bf16(a0, bh, acc[ct], 0, 0, 0);
        acc[ct] = __builtin_amdgcn_mfma_f32_16x16x32_bf16(a0, bm, acc[ct], 0, 0, 0);
        acc[ct] = __builtin_amdgcn_mfma_f32_16x16x32_bf16(a1, bh, acc[ct], 0, 0, 0);
        acc[ct] = __builtin_amdgcn_mfma_f32_16x16x32_bf16(a1, bm, acc[ct], 0, 0, 0);
        if (three)
          acc[ct] = __builtin_amdgcn_mfma_f32_16x16x32_bf16(a2, bh, acc[ct], 0, 0, 0);
      }
    }
  }

  // C layout (verified): col = lane&15, row = (lane>>4)*4 + reg
  __syncthreads();
#pragma unroll
  for (int ct = 0; ct < 2; ++ct)
#pragma unroll
    for (int qq = 0; qq < 4; ++qq)
      epi[(w * 32 + ct * 16 + lr) * 17 + kgq * 4 + qq] = acc[ct][qq];
  __syncthreads();

  const float* bi = p.bih[LAYER][unit];
  const float* bh_ = p.bhh[LAYER][unit];
  float* hF = p.h[LAYER] + (size_t)((s & 1) * 2 + unit) * BB * HH;
  const float* hFp = p.h[LAYER] + (size_t)(pb * 2 + unit) * BB * HH;
  u16* hPl = p.hpl[LAYER] + (size_t)((s & 1) * 2 + unit) * 3 * BB * HH;
  float* cS = p.c[LAYER] + (size_t)unit * BB * HH;
  u16* yPl = p.y0pl + (size_t)unit * 3 * BB * HH;

#pragma unroll
  for (int oi2 = 0; oi2 < 2; ++oi2) {
    const int oi = l + oi2 * 64;
    const int r = oi >> 3, jj = oi & 7;
    const int rg = w * 16 + r;        // batch row
    const int j = jb * 8 + jj;        // hidden index
    float g4[4];
#pragma unroll
    for (int g = 0; g < 4; ++g)
      g4[g] = epi[(w * 32 + g * 8 + jj) * 17 + r] + bi[g * HH + j] + bh_[g * HH + j];
    const bool m = (t < p.lens[rg]);
    const size_t hx = (size_t)rg * HH + j;
    const float c0 = (s > 0) ? cS[hx] : 0.f;
    const float iv = 1.f / (1.f + expf(-g4[0]));
    const float fv = 1.f / (1.f + expf(-g4[1]));
    const float gv = tanhf(g4[2]);
    const float ov = 1.f / (1.f + expf(-g4[3]));
    const float cn = fv * c0 + iv * gv;
    const float hn = ov * tanhf(cn);
    cS[hx] = m ? cn : c0;
    const float hp0 = (s > 0) ? hFp[hx] : 0.f;
    const float hc = m ? hn : hp0;    // carried h (exact f32)
    hF[hx] = hc;
    {
      const u16 h1 = f2bf(hc); const float r1 = hc - bf2f(h1);
      const u16 h2 = f2bf(r1); const float r2 = r1 - bf2f(h2);
      hPl[hx] = h1;
      hPl[(size_t)BB * HH + hx] = h2;
      hPl[(size_t)2 * BB * HH + hx] = f2bf(r2);
    }
    const size_t orow = ((size_t)(dir * TT + t) * BB + rg) * (2 * HH);
    if (LAYER == 0) {
      const float y = m ? hn : 0.f;
      p.out[orow + j] = y;
      const u16 y1 = f2bf(y); const float r1 = y - bf2f(y1);
      const u16 y2 = f2bf(r1); const float r2 = r1 - bf2f(y2);
      yPl[hx] = y1;
      yPl[(size_t)BB * HH + hx] = y2;
      yPl[(size_t)2 * BB * HH + hx] = f2bf(r2);
    } else {
      const float y0v = p.out[orow + j];
      p.out[orow + HH + j] = m ? (hn + y0v) : 0.f;
    }
  }
}

extern "C" void kernel_launch(void* const* d_in, const int* in_sizes, int n_in,
                              void* d_out, int out_size, void* d_ws, size_t ws_size,
                              hipStream_t stream) {
  if (n_in != 19) return;
  if (in_sizes[0] != TT * BB || in_sizes[1] != BB) return;
  if (in_sizes[2] != 32000 * EE) return;
  if (in_sizes[3] != 4 * HH * EE || in_sizes[4] != 4 * HH * HH) return;
  if (in_sizes[7] != 4 * HH * HH || in_sizes[8] != 4 * HH * HH) return;
  if (in_sizes[11] != 4 * HH * EE || in_sizes[15] != 4 * HH * HH) return;
  if (out_size != 2 * TT * BB * 2 * HH) return;
  if (ws_size < 126615552u) return;  // loud fail

  char* ws = (char*)d_ws;
  // weight planes: WA [unit][plane] 12,582,912 B each; WB 16,777,216 B each
  u16* WA = (u16*)ws;                                   // 50,331,648
  u16* WB = (u16*)(ws + 50331648);                      // 67,108,864
  float* hA = (float*)(ws + 117440512);                 //  2,097,152
  u16* hApl = (u16*)(ws + 119537664);                   //  1,572,864
  float* cA = (float*)(ws + 121110528);                 //    524,288
  float* hB = (float*)(ws + 121634816);                 //  2,097,152
  u16* hBpl = (u16*)(ws + 123731968);                   //  1,572,864
  float* cB = (float*)(ws + 125304832);                 //    524,288
  u16* y0pl = (u16*)(ws + 125829120);                   //    786,432

  P p;
  p.ids = (const int*)d_in[0];
  p.lens = (const int*)d_in[1];
  p.emb = (const float*)d_in[2];
  const float* WihA[2] = {(const float*)d_in[3], (const float*)d_in[11]};
  const float* WhhA[2] = {(const float*)d_in[4], (const float*)d_in[12]};
  p.bih[0][0] = (const float*)d_in[5];  p.bhh[0][0] = (const float*)d_in[6];
  p.bih[0][1] = (const float*)d_in[13]; p.bhh[0][1] = (const float*)d_in[14];
  const float* WihB[2] = {(const float*)d_in[7], (const float*)d_in[15]};
  const float* WhhB[2] = {(const float*)d_in[8], (const float*)d_in[16]};
  p.bih[1][0] = (const float*)d_in[9];  p.bhh[1][0] = (const float*)d_in[10];
  p.bih[1][1] = (const float*)d_in[17]; p.bhh[1][1] = (const float*)d_in[18];
  for (int u = 0; u < 2; ++u) {
    p.W[0][u][0] = WA + (size_t)(u * 2 + 0) * 6291456;
    p.W[0][u][1] = WA + (size_t)(u * 2 + 1) * 6291456;
    p.W[1][u][0] = WB + (size_t)(u * 2 + 0) * 8388608;
    p.W[1][u][1] = WB + (size_t)(u * 2 + 1) * 8388608;
  }
  p.out = (float*)d_out;
  p.h[0] = hA; p.h[1] = hB;
  p.hpl[0] = hApl; p.hpl[1] = hBpl;
  p.c[0] = cA; p.c[1] = cB;
  p.y0pl = y0pl;

  for (int u = 0; u < 2; ++u) {
    prep_w<<<4096, 256, 0, stream>>>(WihA[u], WhhA[u], EE, 1536,
                                     (u16*)p.W[0][u][0], (u16*)p.W[0][u][1]);
    prep_w<<<4096, 256, 0, stream>>>(WihB[u], WhhB[u], HH, 2048,
                                     (u16*)p.W[1][u][0], (u16*)p.W[1][u][1]);
  }
  for (int s = 0; s < TT; ++s) {
    step_k<0, 1536, 512, 6><<<256, 256, 0, stream>>>(p, s);
    step_k<1, 2048, 1024, 8><<<256, 256, 0, stream>>>(p, s);
  }
}

// Round 9
// 13594.440 us; speedup vs baseline: 7.6465x; 1.7267x over previous
//
#include <hip/hip_runtime.h>
#include <stdint.h>

#define TT 256
#define BB 64
#define EE 512
#define HH 1024

typedef short s8v __attribute__((ext_vector_type(8)));
typedef float f4v __attribute__((ext_vector_type(4)));
typedef unsigned short u16;

static __device__ __forceinline__ u16 f2bf(float f) {
  uint32_t u = __float_as_uint(f);
  return (u16)((u + 0x7fffu + ((u >> 16) & 1u)) >> 16);  // RNE
}
static __device__ __forceinline__ float bf2f(u16 b) {
  return __uint_as_float(((uint32_t)b) << 16);
}

struct P {
  const int* ids; const int* lens; const float* emb;
  const float* bih[2][2]; const float* bhh[2][2];  // [layer][unit]
  const u16* W[2][2][2];   // [layer][unit][plane hi/mid], frag-ready layout
  float* out;              // [2][T][B][2][H] f32
  float* h[2];             // [layer]: [2buf][2unit][B][H] f32 carried h (exact)
  u16* hpl[2];             // [layer]: [2buf][2unit][2pl][B][H] bf16 planes of h
  float* c[2];             // [layer]: [2unit][B][H] f32
  u16* y0pl;               // [2buf][2unit][2pl][B][H] bf16 planes of masked y0
};

// Split f32 weights into hi/mid bf16 planes, frag-ready layout:
// dst[jb][kt][kg][c][e], k = kt*32+kg*8+e, gate-col n = (c>>3)*H + jb*8 + (c&7)
__global__ void prep_w(const float* Wih, const float* Whh, int KX, int K,
                       u16* dH, u16* dM) {
  const size_t total = (size_t)128 * K * 32;
  for (size_t idx = (size_t)blockIdx.x * 256 + threadIdx.x; idx < total;
       idx += (size_t)gridDim.x * 256) {
    const int c = (int)(idx & 31);
    const int k = (int)((idx >> 5) % K);
    const int jb = (int)(idx / ((size_t)K * 32));
    const int n = (c >> 3) * HH + jb * 8 + (c & 7);
    const float v = (k < KX) ? Wih[(size_t)n * KX + k] : Whh[(size_t)n * HH + (k - KX)];
    const u16 h = f2bf(v);
    const u16 m = f2bf(v - bf2f(h));
    const size_t off = ((size_t)jb * (K / 32) + (k >> 5)) * 1024 +
                       ((k >> 3) & 3) * 256 + c * 8 + (k & 7);
    dH[off] = h; dM[off] = m;
  }
}

// One layer, one time step, both directions. ub = unit*128 + jb.
// block 256 = 4 waves; wave = 16 batch rows x 32 gate-cols; K chunked by 8 kt.
template <int LAYER, int K, int KX, int NST>
static __device__ __forceinline__ void run_layer(const P& p, int s, int ub,
                                                 u16 (*lds)[8192], float* epi) {
  const int tid = threadIdx.x;
  const int w = tid >> 6, l = tid & 63, lr = l & 15, kgq = l >> 4;
  const int unit = ub >> 7;
  const int jb = ub & 127;
  const int dir = unit;
  const int t = dir ? (TT - 1 - s) : s;
  const int row = w * 16 + lr;

  const u16* WH = p.W[LAYER][unit][0] + (size_t)jb * (K / 32) * 1024;
  const u16* WM = p.W[LAYER][unit][1] + (size_t)jb * (K / 32) * 1024;
  const uint4* gH = (const uint4*)WH;
  const uint4* gM = (const uint4*)WM;

  const u16* hp2 = p.hpl[LAYER] + (size_t)((((s - 1) & 1) * 2 + unit) * 2) * BB * HH;
  const u16* y2  = p.y0pl + (size_t)(((s & 1) * 2 + unit) * 2) * BB * HH;
  const float* xsrc = nullptr;
  if (LAYER == 0) {
    const int id = p.ids[t * BB + row];
    xsrc = p.emb + (size_t)id * EE;
  }

  f4v acc[2];
  { f4v z = {0.f, 0.f, 0.f, 0.f}; acc[0] = z; acc[1] = z; }

  uint4 rH[4], rM[4];
  // prologue: stage chunk 0
#pragma unroll
  for (int i = 0; i < 4; ++i) { rH[i] = gH[i * 256 + tid]; rM[i] = gM[i * 256 + tid]; }
  {
    uint4* dH = (uint4*)lds[0]; uint4* dM = (uint4*)lds[1];
#pragma unroll
    for (int i = 0; i < 4; ++i) { dH[i * 256 + tid] = rH[i]; dM[i * 256 + tid] = rM[i]; }
  }
  __syncthreads();

  int cur = 0;
  for (int q = 0; q < NST; ++q) {
    if (q + 1 < NST) {  // issue next chunk's global loads early (latency hides)
#pragma unroll
      for (int i = 0; i < 4; ++i) {
        rH[i] = gH[(size_t)(q + 1) * 1024 + i * 256 + tid];
        rM[i] = gM[(size_t)(q + 1) * 1024 + i * 256 + tid];
      }
    }
    const u16* lH = lds[cur * 2 + 0];
    const u16* lM = lds[cur * 2 + 1];
    for (int ktl = 0; ktl < 8; ++ktl) {
      const int ktg = q * 8 + ktl;
      const int k0 = ktg * 32 + kgq * 8;
      s8v a0, a1;
      if (LAYER == 0 && k0 < KX) {          // x: gather + on-the-fly hi/mid split
        const float4 f0 = *(const float4*)(xsrc + k0);
        const float4 f1 = *(const float4*)(xsrc + k0 + 4);
        const float tf[8] = {f0.x, f0.y, f0.z, f0.w, f1.x, f1.y, f1.z, f1.w};
#pragma unroll
        for (int e = 0; e < 8; ++e) {
          const u16 hh = f2bf(tf[e]);
          a0[e] = (short)hh;
          a1[e] = (short)f2bf(tf[e] - bf2f(hh));
        }
      } else if (LAYER == 1 && k0 < KX) {   // y0 planes (written by L0, prev dispatch)
        const size_t o = (size_t)row * HH + k0;
        a0 = *(const s8v*)(y2 + o);
        a1 = *(const s8v*)(y2 + (size_t)BB * HH + o);
      } else {                              // recurrent h planes
        if (s == 0) continue;
        const size_t o = (size_t)row * HH + (k0 - KX);
        a0 = *(const s8v*)(hp2 + o);
        a1 = *(const s8v*)(hp2 + (size_t)BB * HH + o);
      }
#pragma unroll
      for (int ct = 0; ct < 2; ++ct) {
        const int bo = ((ktl * 4 + kgq) * 32 + ct * 16 + lr) * 8;
        const s8v bh = *(const s8v*)(lH + bo);
        const s8v bm = *(const s8v*)(lM + bo);
        acc[ct] = __builtin_amdgcn_mfma_f32_16x16x32_bf16(a0, bh, acc[ct], 0, 0, 0);
        acc[ct] = __builtin_amdgcn_mfma_f32_16x16x32_bf16(a0, bm, acc[ct], 0, 0, 0);
        acc[ct] = __builtin_amdgcn_mfma_f32_16x16x32_bf16(a1, bh, acc[ct], 0, 0, 0);
      }
    }
    if (q + 1 < NST) {  // write next chunk into the other buffer
      uint4* dH = (uint4*)lds[(cur ^ 1) * 2 + 0];
      uint4* dM = (uint4*)lds[(cur ^ 1) * 2 + 1];
#pragma unroll
      for (int i = 0; i < 4; ++i) { dH[i * 256 + tid] = rH[i]; dM[i * 256 + tid] = rM[i]; }
    }
    __syncthreads();
    cur ^= 1;
  }

  // C layout: col = lane&15, row = (lane>>4)*4 + reg
#pragma unroll
  for (int ct = 0; ct < 2; ++ct)
#pragma unroll
    for (int qq = 0; qq < 4; ++qq)
      epi[(w * 32 + ct * 16 + lr) * 17 + kgq * 4 + qq] = acc[ct][qq];
  __syncthreads();

  const float* bi = p.bih[LAYER][unit];
  const float* bh_ = p.bhh[LAYER][unit];
  float* hF = p.h[LAYER] + (size_t)((s & 1) * 2 + unit) * BB * HH;
  const float* hFp = p.h[LAYER] + (size_t)(((s - 1) & 1) * 2 + unit) * BB * HH;
  u16* hPl = p.hpl[LAYER] + (size_t)(((s & 1) * 2 + unit) * 2) * BB * HH;
  float* cS = p.c[LAYER] + (size_t)unit * BB * HH;
  u16* yPl = p.y0pl + (size_t)(((s & 1) * 2 + unit) * 2) * BB * HH;

#pragma unroll
  for (int oi2 = 0; oi2 < 2; ++oi2) {
    const int oi = l + oi2 * 64;
    const int r = oi >> 3, jj = oi & 7;
    const int rg = w * 16 + r;        // batch row
    const int j = jb * 8 + jj;        // hidden index
    float g4[4];
#pragma unroll
    for (int g = 0; g < 4; ++g)
      g4[g] = epi[(w * 32 + g * 8 + jj) * 17 + r] + bi[g * HH + j] + bh_[g * HH + j];
    const bool m = (t < p.lens[rg]);
    const size_t hx = (size_t)rg * HH + j;
    const float c0 = (s > 0) ? cS[hx] : 0.f;
    const float iv = 1.f / (1.f + expf(-g4[0]));
    const float fv = 1.f / (1.f + expf(-g4[1]));
    const float gv = tanhf(g4[2]);
    const float ov = 1.f / (1.f + expf(-g4[3]));
    const float cn = fv * c0 + iv * gv;
    const float hn = ov * tanhf(cn);
    cS[hx] = m ? cn : c0;
    const float hp0 = (s > 0) ? hFp[hx] : 0.f;
    const float hc = m ? hn : hp0;    // carried h (exact f32)
    hF[hx] = hc;
    const u16 h1 = f2bf(hc);
    const u16 h2 = f2bf(hc - bf2f(h1));
    hPl[hx] = h1;
    hPl[(size_t)BB * HH + hx] = h2;
    const size_t orow = ((size_t)(dir * TT + t) * BB + rg) * (2 * HH);
    if (LAYER == 0) {
      const float y = m ? hn : 0.f;
      p.out[orow + j] = y;
      const u16 y1 = f2bf(y);
      const u16 ylo = f2bf(y - bf2f(y1));
      yPl[hx] = y1;
      yPl[(size_t)BB * HH + hx] = ylo;
    } else {
      const float y0v = p.out[orow + j];
      p.out[orow + HH + j] = m ? (hn + y0v) : 0.f;
    }
  }
}

// Pipelined dispatch: blocks 0-255 run layer0 @ step sd; 256-511 layer1 @ sd-1.
__global__ __launch_bounds__(256, 2) void step_fused(P p, int sd) {
  __shared__ __align__(16) u16 lds[4][8192];   // [buf*2+plane][8 kt * 1024] = 64 KB
  __shared__ float epi[4 * 32 * 17];           // 8.7 KB
  const int bid = blockIdx.x;
  if (bid < 256) {
    if (sd < TT) run_layer<0, 1536, 512, 6>(p, sd, bid, lds, epi);
  } else {
    if (sd >= 1) run_layer<1, 2048, 1024, 8>(p, sd - 1, bid - 256, lds, epi);
  }
}

extern "C" void kernel_launch(void* const* d_in, const int* in_sizes, int n_in,
                              void* d_out, int out_size, void* d_ws, size_t ws_size,
                              hipStream_t stream) {
  if (n_in != 19) return;
  if (in_sizes[0] != TT * BB || in_sizes[1] != BB) return;
  if (in_sizes[2] != 32000 * EE) return;
  if (in_sizes[3] != 4 * HH * EE || in_sizes[4] != 4 * HH * HH) return;
  if (in_sizes[7] != 4 * HH * HH || in_sizes[8] != 4 * HH * HH) return;
  if (in_sizes[11] != 4 * HH * EE || in_sizes[15] != 4 * HH * HH) return;
  if (out_size != 2 * TT * BB * 2 * HH) return;
  if (ws_size < 123731968u) return;  // loud fail

  char* ws = (char*)d_ws;
  u16* WA = (u16*)ws;                       // 50,331,648 B
  u16* WB = (u16*)(ws + 50331648);          // 67,108,864 B
  float* hA = (float*)(ws + 117440512);     //  1,048,576 B
  u16* hApl = (u16*)(ws + 118489088);       //  1,048,576 B
  float* cA = (float*)(ws + 119537664);     //    524,288 B
  float* hB = (float*)(ws + 120061952);     //  1,048,576 B
  u16* hBpl = (u16*)(ws + 121110528);       //  1,048,576 B
  float* cB = (float*)(ws + 122159104);     //    524,288 B
  u16* y0pl = (u16*)(ws + 122683392);       //  1,048,576 B  -> end 123,731,968

  P p;
  p.ids = (const int*)d_in[0];
  p.lens = (const int*)d_in[1];
  p.emb = (const float*)d_in[2];
  const float* WihA[2] = {(const float*)d_in[3], (const float*)d_in[11]};
  const float* WhhA[2] = {(const float*)d_in[4], (const float*)d_in[12]};
  p.bih[0][0] = (const float*)d_in[5];  p.bhh[0][0] = (const float*)d_in[6];
  p.bih[0][1] = (const float*)d_in[13]; p.bhh[0][1] = (const float*)d_in[14];
  const float* WihB[2] = {(const float*)d_in[7], (const float*)d_in[15]};
  const float* WhhB[2] = {(const float*)d_in[8], (const float*)d_in[16]};
  p.bih[1][0] = (const float*)d_in[9];  p.bhh[1][0] = (const float*)d_in[10];
  p.bih[1][1] = (const float*)d_in[17]; p.bhh[1][1] = (const float*)d_in[18];
  for (int u = 0; u < 2; ++u) {
    p.W[0][u][0] = WA + (size_t)(u * 2 + 0) * 6291456;
    p.W[0][u][1] = WA + (size_t)(u * 2 + 1) * 6291456;
    p.W[1][u][0] = WB + (size_t)(u * 2 + 0) * 8388608;
    p.W[1][u][1] = WB + (size_t)(u * 2 + 1) * 8388608;
  }
  p.out = (float*)d_out;
  p.h[0] = hA; p.h[1] = hB;
  p.hpl[0] = hApl; p.hpl[1] = hBpl;
  p.c[0] = cA; p.c[1] = cB;
  p.y0pl = y0pl;

  for (int u = 0; u < 2; ++u) {
    prep_w<<<4096, 256, 0, stream>>>(WihA[u], WhhA[u], EE, 1536,
                                     (u16*)p.W[0][u][0], (u16*)p.W[0][u][1]);
    prep_w<<<4096, 256, 0, stream>>>(WihB[u], WhhB[u], HH, 2048,
                                     (u16*)p.W[1][u][0], (u16*)p.W[1][u][1]);
  }
  for (int sd = 0; sd <= TT; ++sd)
    step_fused<<<512, 256, 0, stream>>>(p, sd);
}